// Round 8
// baseline (320.500 us; speedup 1.0000x reference)
//
#include <hip/hip_runtime.h>

#define T_LEN 131072
#define KDIM 128
#define CHUNK 64
#define WARM 16
#define NCHUNK 2048   // ceil(131071/64)

typedef float v2f __attribute__((ext_vector_type(2)));

__device__ __forceinline__ void decode4(unsigned int pk, float& e0, float& e1, float& e2, float& e3) {
    v2f lo = __builtin_amdgcn_cvt_pk_f32_fp8((int)pk, false);
    v2f hi = __builtin_amdgcn_cvt_pk_f32_fp8((int)pk, true);
    e0 = lo.x; e1 = lo.y; e2 = hi.x; e3 = hi.y;
}

__device__ __forceinline__ int trans_idx(int w2w, int ic, int dist) {
    return (w2w == 1) ? 0 : (ic == 0 ? 1 : (dist == 0 ? 2 : 3));
}

__device__ __forceinline__ float wave_sum(float x) {
    #pragma unroll
    for (int off = 32; off; off >>= 1) x += __shfl_xor(x, off, 64);
    return x;
}

// ---- prep: idxArr + fp8 E in per-lane interleaved layout ----
// dword index D = m*4096 + k4*256 + p*4 + e  (k4=uint4 idx 0..15, e=dword 0..3)
// lane-local dword w = 4*k4+e in [0,64): col j = 2p + (w>>5), rows 4*(w&31)+a in byte a.
// In-kernel read: uint4 idx = m*1024 + k4*64 + lane  -> wave reads contiguous 1KB, conflict-free.
__global__ void prep_kernel(const float* __restrict__ trans,
                            const int* __restrict__ w2w, const int* __restrict__ ic,
                            const int* __restrict__ dist,
                            unsigned int* __restrict__ Eswz, unsigned char* __restrict__ idxArr) {
    int tid = blockIdx.x * blockDim.x + threadIdx.x;
    if (tid < T_LEN - 1) idxArr[tid] = (unsigned char)trans_idx(w2w[tid], ic[tid], dist[tid]);
    if (tid < 16384) {
        const int m = tid >> 12, r = tid & 4095;
        const int k4 = r >> 8, p = (r >> 2) & 63, e = r & 3;
        const int w = (k4 << 2) | e;
        const int c = w >> 5, i4 = w & 31;
        const int j = (p << 1) + c;
        unsigned int out = 0;
        #pragma unroll
        for (int a = 0; a < 4; ++a) {
            float ev = __expf(trans[((size_t)m << 14) + (((i4 << 2) + a) << 7) + j]);
            unsigned int u = __float_as_uint(ev) - 0x3C000000u;        // rebias to e4m3 at bit20
            unsigned int b = (u + 0x7FFFFu + ((u >> 20) & 1u)) >> 20;  // RNE
            out |= (b & 0xffu) << (8 * a);
        }
        Eswz[tid] = out;
    }
}

// ---- gold: parallel gather + reduce ----
__global__ void gold_kernel(const float* __restrict__ em, const float* __restrict__ trans,
                            const float* __restrict__ start, const float* __restrict__ cw,
                            const int* __restrict__ tags, const int* __restrict__ w2w,
                            const int* __restrict__ ic, const int* __restrict__ dist,
                            double* __restrict__ gold_acc) {
    int tid = blockIdx.x * blockDim.x + threadIdx.x;
    int stride = gridDim.x * blockDim.x;
    float part = 0.f;
    for (int t = tid; t < T_LEN; t += stride) {
        int tg = tags[t];
        float wt = cw[tg];
        float emv = em[(size_t)t * KDIM + tg];
        if (t == 0) {
            part += wt * (start[tg] + emv);
        } else {
            int m = trans_idx(w2w[t - 1], ic[t - 1], dist[t - 1]);
            int tgp = tags[t - 1];
            part += wt * (trans[((size_t)m * KDIM + tgp) * KDIM + tg] + emv);
        }
    }
    __shared__ float red[256];
    red[threadIdx.x] = part;
    __syncthreads();
    for (int s = 128; s > 0; s >>= 1) {
        if (threadIdx.x < (unsigned)s) red[threadIdx.x] += red[threadIdx.x + s];
        __syncthreads();
    }
    if (threadIdx.x == 0) atomicAdd(gold_acc, (double)red[0]);
}

// ---- scan: ONE WAVE PER CHUNK, no barriers in the loop ----
// Lane p owns columns 2p,2p+1; v broadcast via v_readlane; E from LDS fp8.
__global__ void __launch_bounds__(256, 2) scan_kernel(
    const float* __restrict__ em, const unsigned int* __restrict__ Eswz,
    const unsigned char* __restrict__ idxArr, const float* __restrict__ start,
    double* __restrict__ logz_acc)
{
    const int wave = threadIdx.x >> 6;
    const int lane = threadIdx.x & 63;
    const int c    = (blockIdx.x << 2) | wave;

    __shared__ unsigned int EL[16384];   // 64 KB: all 4 fp8 matrices

    // ---- stage E (whole block cooperates), single barrier ----
    #pragma unroll
    for (int w = 0; w < 16; ++w) {
        const int i4x = (w << 8) + threadIdx.x;   // uint4 index 0..4095
        reinterpret_cast<uint4*>(EL)[i4x] = reinterpret_cast<const uint4*>(Eswz)[i4x];
    }
    __syncthreads();

    const int t_own = 1 + c * CHUNK;
    const int t_end = min(t_own + CHUNK, T_LEN);
    const int t0    = (c == 0) ? 1 : (t_own - WARM);

    // ---- init v (lane owns cols 2*lane, 2*lane+1) ----
    float vlo, vhi;
    if (c == 0) {
        vlo = __expf(start[2 * lane]     + em[2 * lane]);
        vhi = __expf(start[2 * lane + 1] + em[2 * lane + 1]);
    } else {
        vlo = 1.f; vhi = 1.f;
    }
    const float s0 = wave_sum(vlo + vhi);
    float scale = 1.0f / s0;
    float g = (c == 0) ? __logf(s0) : 0.f;

    // ---- prefetch step t0 ----
    int pm = idxArr[t0 - 1];
    float2 em2 = *reinterpret_cast<const float2*>(&em[(size_t)t0 * KDIM + 2 * lane]);

    for (int t = t0; t < t_end; ++t) {
        const int m = pm;
        const float d0 = __expf(em2.x);
        const float d1 = __expf(em2.y);

        // prefetch next step (clamped)
        const int tn = min(t + 1, T_LEN - 1);
        pm = idxArr[tn - 1];
        em2 = *reinterpret_cast<const float2*>(&em[(size_t)tn * KDIM + 2 * lane]);

        // load this step's 256B of E (16 x b128, conflict-free)
        const uint4* Ep = reinterpret_cast<const uint4*>(EL) + (m << 10);
        unsigned int ur[64];
        #pragma unroll
        for (int k = 0; k < 16; ++k) {
            const uint4 q = Ep[(k << 6) + lane];
            ur[(k << 2)]     = q.x;
            ur[(k << 2) + 1] = q.y;
            ur[(k << 2) + 2] = q.z;
            ur[(k << 2) + 3] = q.w;
        }

        // matvec: a0 = sum_i v[i]*E[i][2p], a1 = sum_i v[i]*E[i][2p+1]
        const unsigned int vlo_u = __float_as_uint(vlo);
        const unsigned int vhi_u = __float_as_uint(vhi);
        float a0 = 0.f, a1 = 0.f;
        #pragma unroll
        for (int i4 = 0; i4 < 32; ++i4) {
            const float w0 = __uint_as_float(__builtin_amdgcn_readlane(vlo_u, 2 * i4));
            const float w1 = __uint_as_float(__builtin_amdgcn_readlane(vhi_u, 2 * i4));
            const float w2 = __uint_as_float(__builtin_amdgcn_readlane(vlo_u, 2 * i4 + 1));
            const float w3 = __uint_as_float(__builtin_amdgcn_readlane(vhi_u, 2 * i4 + 1));
            float e0, e1, e2, e3;
            decode4(ur[i4], e0, e1, e2, e3);            // col 2p, rows 4*i4..4*i4+3
            a0 = fmaf(w0, e0, a0); a0 = fmaf(w1, e1, a0);
            a0 = fmaf(w2, e2, a0); a0 = fmaf(w3, e3, a0);
            decode4(ur[32 + i4], e0, e1, e2, e3);       // col 2p+1
            a1 = fmaf(w0, e0, a1); a1 = fmaf(w1, e1, a1);
            a1 = fmaf(w2, e2, a1); a1 = fmaf(w3, e3, a1);
        }

        // emission + lazy renorm, wave reduce (every step; v stays O(1))
        const float n0 = a0 * d0 * scale;
        const float n1 = a1 * d1 * scale;
        const float s  = wave_sum(n0 + n1);
        scale = 1.0f / s;
        if (t >= t_own) g += __logf(s);
        vlo = n0; vhi = n1;
    }

    if (lane == 0) atomicAdd(logz_acc, (double)g);
}

__global__ void finalize_kernel(const double* __restrict__ acc, float* __restrict__ out) {
    if (threadIdx.x == 0 && blockIdx.x == 0) {
        out[0] = (float)acc[0];
        out[1] = (float)acc[1];
    }
}

extern "C" void kernel_launch(void* const* d_in, const int* in_sizes, int n_in,
                              void* d_out, int out_size, void* d_ws, size_t ws_size,
                              hipStream_t stream) {
    const float* emissions = (const float*)d_in[0];
    const float* trans     = (const float*)d_in[1];
    const float* start     = (const float*)d_in[2];
    const float* cw        = (const float*)d_in[3];
    const int*   tags      = (const int*)d_in[4];
    const int*   w2w       = (const int*)d_in[5];
    const int*   icnt      = (const int*)d_in[6];
    const int*   dist      = (const int*)d_in[7];

    double*        accs   = (double*)d_ws;                         // [0]=gold, [1]=logz
    unsigned int*  Eswz   = (unsigned int*)((char*)d_ws + 64);     // 65536 B fp8, lane-interleaved
    unsigned char* idxArr = (unsigned char*)d_ws + 64 + 65536;     // T-1 bytes

    hipMemsetAsync(d_ws, 0, 16, stream);
    prep_kernel<<<512, 256, 0, stream>>>(trans, w2w, icnt, dist, Eswz, idxArr);
    gold_kernel<<<512, 256, 0, stream>>>(emissions, trans, start, cw, tags, w2w, icnt, dist, &accs[0]);
    scan_kernel<<<NCHUNK / 4, 256, 0, stream>>>(emissions, Eswz, idxArr, start, &accs[1]);
    finalize_kernel<<<1, 64, 0, stream>>>(accs, (float*)d_out);
}

// Round 9
// 244.867 us; speedup vs baseline: 1.3089x; 1.3089x over previous
//
#include <hip/hip_runtime.h>

#define T_LEN 131072
#define KDIM 128
#define CHUNK 128
#define WARM 16
#define NSTEP (CHUNK + WARM)
#define NCHUNK 1024   // ceil(131071/128); 2 pipes/block -> 512 blocks = 2/CU

typedef float v2f __attribute__((ext_vector_type(2)));

__device__ __forceinline__ void decode4(unsigned int pk, float& e0, float& e1, float& e2, float& e3) {
    v2f lo = __builtin_amdgcn_cvt_pk_f32_fp8((int)pk, false);
    v2f hi = __builtin_amdgcn_cvt_pk_f32_fp8((int)pk, true);
    e0 = lo.x; e1 = lo.y; e2 = hi.x; e3 = hi.y;
}

__device__ __forceinline__ int trans_idx(int w2w, int ic, int dist) {
    return (w2w == 1) ? 0 : (ic == 0 ? 1 : (dist == 0 ? 2 : 3));
}

// pack two floats into bf16 pair (RNE), x in low half, y in high half
__device__ __forceinline__ unsigned bf16pair(float x, float y) {
    unsigned ux = __float_as_uint(x);
    ux = (ux + 0x7fffu + ((ux >> 16) & 1u)) >> 16;
    unsigned uy = __float_as_uint(y);
    uy = (uy + 0x7fffu + ((uy >> 16) & 1u)) & 0xffff0000u;
    return ux | uy;
}

// ---- fused prep (idxArr + swizzled fp8 E) + gold ----
// E dword index D = m*4096 + k4*512 + L*4 + a  (L = pipe-lane 0..127, a = row-in-quad)
// holds fp8x4 of exp(trans[m][row][col+j]), row = 32*(L>>5) + 4*k4 + a, col = 4*(L&31).
// In-kernel quad index Q = m*1024 + k4*128 + L -> wave reads consecutive uint4, conflict-free.
__global__ void prep_gold_kernel(const float* __restrict__ em, const float* __restrict__ trans,
                                 const float* __restrict__ start, const float* __restrict__ cw,
                                 const int* __restrict__ tags, const int* __restrict__ w2w,
                                 const int* __restrict__ ic, const int* __restrict__ dist,
                                 unsigned int* __restrict__ Eswz, unsigned char* __restrict__ idxArr,
                                 double* __restrict__ goldslots) {
    const int tid = blockIdx.x * blockDim.x + threadIdx.x;   // 0..131071
    if (tid < T_LEN - 1) idxArr[tid] = (unsigned char)trans_idx(w2w[tid], ic[tid], dist[tid]);
    if (tid < 16384) {
        const int m = tid >> 12, r = tid & 4095;
        const int k4 = r >> 9, L = (r >> 2) & 127, a = r & 3;
        const int row = ((L >> 5) << 5) + (k4 << 2) + a;
        const int col = (L & 31) << 2;
        const float* src = trans + ((size_t)m << 14) + (row << 7) + col;
        unsigned int out = 0;
        #pragma unroll
        for (int j = 0; j < 4; ++j) {
            float ev = __expf(src[j]);
            unsigned int u = __float_as_uint(ev) - 0x3C000000u;        // rebias to e4m3 at bit20
            unsigned int b = (u + 0x7FFFFu + ((u >> 20) & 1u)) >> 20;  // RNE
            out |= (b & 0xffu) << (8 * j);
        }
        Eswz[tid] = out;
    }
    // gold: one t per thread (grid covers T exactly)
    float part = 0.f;
    {
        const int t = tid;
        const int tg = tags[t];
        const float wt = cw[tg];
        const float emv = em[(size_t)t * KDIM + tg];
        if (t == 0) {
            part = wt * (start[tg] + emv);
        } else {
            const int m = trans_idx(w2w[t - 1], ic[t - 1], dist[t - 1]);
            part = wt * (trans[((size_t)m * KDIM + tags[t - 1]) * KDIM + tg] + emv);
        }
    }
    __shared__ float red[256];
    red[threadIdx.x] = part;
    __syncthreads();
    for (int s = 128; s > 0; s >>= 1) {
        if (threadIdx.x < (unsigned)s) red[threadIdx.x] += red[threadIdx.x + s];
        __syncthreads();
    }
    if (threadIdx.x == 0) goldslots[blockIdx.x] = (double)red[0];
}

// ---- scan: 2 pipes x 128 threads share one fp8 LDS copy of all 4 E ----
// Pipe-lane tau: p=tau&31 (cols 4p..4p+3), h=tau>>5 (rows 32h..32h+31).
// v in LDS as bf16 pairs (f32-range exponent -> no overflow with norm-every-8).
__global__ void __launch_bounds__(256) scan_kernel(
    const float* __restrict__ em, const uint4* __restrict__ Eswz,
    const unsigned char* __restrict__ idxArr, const float* __restrict__ start,
    double* __restrict__ logzslots)
{
    const int pipe = threadIdx.x >> 7;      // 0 or 1
    const int tau  = threadIdx.x & 127;     // pipe-local thread id
    const int c    = (blockIdx.x << 1) | pipe;
    const int p    = tau & 31;
    const int h    = tau >> 5;              // 0..3

    __shared__ uint4 EL[4096];                           // 64 KB: all 4 fp8 matrices
    __shared__ unsigned v16[2][64];                      // v as bf16 pairs, per pipe
    __shared__ __align__(16) float partial[2][4][KDIM];  // 4 KB
    __shared__ float wsum[2][2];

    // ---- stage E (whole block cooperates) ----
    #pragma unroll
    for (int w = 0; w < 16; ++w) {
        const int q = (w << 8) + threadIdx.x;
        EL[q] = Eswz[q];
    }

    const int t_own = 1 + c * CHUNK;
    const int t_end = min(t_own + CHUNK, T_LEN);
    const int t0    = (c == 0) ? 1 : (t_own - WARM);

    // ---- init v (all 128 threads active) ----
    float myv = (c == 0) ? __expf(start[tau] + em[tau]) : 1.0f;
    {
        const float other = __shfl_xor(myv, 1, 64);
        if (!(tau & 1)) v16[pipe][tau >> 1] = bf16pair(myv, other);
    }
    float r0 = myv;
    #pragma unroll
    for (int off = 32; off; off >>= 1) r0 += __shfl_down(r0, off, 64);
    if ((tau & 63) == 0) wsum[pipe][tau >> 6] = r0;
    __syncthreads();   // covers EL staging + v16 init + wsum
    const float s0 = wsum[pipe][0] + wsum[pipe][1];
    float scale = 1.0f / s0;

    float g = (c == 0) ? __logf(s0) : 0.f;

    // ---- prefetch step t0 ----
    int   pm = idxArr[t0 - 1];
    float em_pref = em[(size_t)t0 * KDIM + tau];

    for (int it = 0; it < NSTEP; ++it) {
        const int t = t0 + it;
        const bool live = (t < t_end);
        const int m = pm;
        const float d = __expf(em_pref);

        // prefetch next step (clamped in-bounds)
        const int tn = min(t + 1, T_LEN - 1);
        pm = idxArr[tn - 1];
        em_pref = em[(size_t)tn * KDIM + tau];

        // phase 1: 128 MACs: rows 32h..32h+31, cols 4p..4p+3
        const uint4* Eq = EL + (m << 10) + tau;          // stride 128 quads per k4
        const uint4* vq = reinterpret_cast<const uint4*>(&v16[pipe][h << 4]);
        float a0 = 0.f, a1 = 0.f, a2 = 0.f, a3 = 0.f;
        #pragma unroll
        for (int j2 = 0; j2 < 4; ++j2) {
            const uint4 vv = vq[j2];                     // 8 rows (4 pair-dwords)
            const uint4 qa = Eq[(j2 << 1) << 7];         // rows 8*j2 .. +3
            const uint4 qb = Eq[((j2 << 1) + 1) << 7];   // rows 8*j2+4 .. +7
            float e0, e1, e2, e3, w0, w1;
            w0 = __uint_as_float(vv.x << 16);  w1 = __uint_as_float(vv.x & 0xffff0000u);
            decode4(qa.x, e0, e1, e2, e3);
            a0 = fmaf(w0, e0, a0); a1 = fmaf(w0, e1, a1); a2 = fmaf(w0, e2, a2); a3 = fmaf(w0, e3, a3);
            decode4(qa.y, e0, e1, e2, e3);
            a0 = fmaf(w1, e0, a0); a1 = fmaf(w1, e1, a1); a2 = fmaf(w1, e2, a2); a3 = fmaf(w1, e3, a3);
            w0 = __uint_as_float(vv.y << 16);  w1 = __uint_as_float(vv.y & 0xffff0000u);
            decode4(qa.z, e0, e1, e2, e3);
            a0 = fmaf(w0, e0, a0); a1 = fmaf(w0, e1, a1); a2 = fmaf(w0, e2, a2); a3 = fmaf(w0, e3, a3);
            decode4(qa.w, e0, e1, e2, e3);
            a0 = fmaf(w1, e0, a0); a1 = fmaf(w1, e1, a1); a2 = fmaf(w1, e2, a2); a3 = fmaf(w1, e3, a3);
            w0 = __uint_as_float(vv.z << 16);  w1 = __uint_as_float(vv.z & 0xffff0000u);
            decode4(qb.x, e0, e1, e2, e3);
            a0 = fmaf(w0, e0, a0); a1 = fmaf(w0, e1, a1); a2 = fmaf(w0, e2, a2); a3 = fmaf(w0, e3, a3);
            decode4(qb.y, e0, e1, e2, e3);
            a0 = fmaf(w1, e0, a0); a1 = fmaf(w1, e1, a1); a2 = fmaf(w1, e2, a2); a3 = fmaf(w1, e3, a3);
            w0 = __uint_as_float(vv.w << 16);  w1 = __uint_as_float(vv.w & 0xffff0000u);
            decode4(qb.z, e0, e1, e2, e3);
            a0 = fmaf(w0, e0, a0); a1 = fmaf(w0, e1, a1); a2 = fmaf(w0, e2, a2); a3 = fmaf(w0, e3, a3);
            decode4(qb.w, e0, e1, e2, e3);
            a0 = fmaf(w1, e0, a0); a1 = fmaf(w1, e1, a1); a2 = fmaf(w1, e2, a2); a3 = fmaf(w1, e3, a3);
        }
        *reinterpret_cast<float4*>(&partial[pipe][h][p << 2]) = make_float4(a0, a1, a2, a3);
        __syncthreads();

        // phase 2: combine 4 partials, apply emission + pending scale, repack v
        const bool donorm = ((t & 7) == 0) || (t == T_LEN - 1);
        const float tot = (partial[pipe][0][tau] + partial[pipe][1][tau] +
                           partial[pipe][2][tau] + partial[pipe][3][tau]) * (d * scale);
        {
            const float other = __shfl_xor(tot, 1, 64);
            if (live && !(tau & 1)) v16[pipe][tau >> 1] = bf16pair(tot, other);
        }
        if (donorm) {
            float r = tot;
            #pragma unroll
            for (int off = 32; off; off >>= 1) r += __shfl_down(r, off, 64);
            if ((tau & 63) == 0) wsum[pipe][tau >> 6] = r;
        }
        __syncthreads();
        if (donorm) {
            const float s = wsum[pipe][0] + wsum[pipe][1];
            scale = 1.0f / s;
            if (tau == 0 && t >= t_own && t < t_end) g += __logf(s);
        } else {
            scale = 1.0f;
        }
    }

    if (tau == 0) logzslots[c] = (double)g;
}

__global__ void finalize_kernel(const double* __restrict__ goldslots,
                                const double* __restrict__ logzslots,
                                float* __restrict__ out) {
    __shared__ double red[256];
    const int i = threadIdx.x;
    red[i] = goldslots[i] + goldslots[i + 256];
    __syncthreads();
    for (int s = 128; s > 0; s >>= 1) {
        if (i < s) red[i] += red[i + s];
        __syncthreads();
    }
    if (i == 0) out[0] = (float)red[0];
    __syncthreads();
    red[i] = logzslots[i] + logzslots[i + 256] + logzslots[i + 512] + logzslots[i + 768];
    __syncthreads();
    for (int s = 128; s > 0; s >>= 1) {
        if (i < s) red[i] += red[i + s];
        __syncthreads();
    }
    if (i == 0) out[1] = (float)red[0];
}

extern "C" void kernel_launch(void* const* d_in, const int* in_sizes, int n_in,
                              void* d_out, int out_size, void* d_ws, size_t ws_size,
                              hipStream_t stream) {
    const float* emissions = (const float*)d_in[0];
    const float* trans     = (const float*)d_in[1];
    const float* start     = (const float*)d_in[2];
    const float* cw        = (const float*)d_in[3];
    const int*   tags      = (const int*)d_in[4];
    const int*   w2w       = (const int*)d_in[5];
    const int*   icnt      = (const int*)d_in[6];
    const int*   dist      = (const int*)d_in[7];

    double*        goldslots = (double*)d_ws;                         // 512 doubles
    double*        logzslots = (double*)d_ws + 512;                   // 1024 doubles
    unsigned int*  Eswz      = (unsigned int*)((char*)d_ws + 12288);  // 64 KB
    unsigned char* idxArr    = (unsigned char*)d_ws + 12288 + 65536;  // T-1 bytes

    prep_gold_kernel<<<512, 256, 0, stream>>>(emissions, trans, start, cw, tags, w2w,
                                              icnt, dist, Eswz, idxArr, goldslots);
    scan_kernel<<<NCHUNK / 2, 256, 0, stream>>>(emissions, (const uint4*)Eswz, idxArr,
                                                start, logzslots);
    finalize_kernel<<<1, 256, 0, stream>>>(goldslots, logzslots, (float*)d_out);
}

// Round 10
// 240.664 us; speedup vs baseline: 1.3317x; 1.0175x over previous
//
#include <hip/hip_runtime.h>

#define T_LEN 131072
#define KDIM 128
#define CHUNK 64
#define WARM 16
#define NSTEP (CHUNK + WARM)
#define NCHUNK 2048   // 512 blocks x 4 pipes

typedef float v2f __attribute__((ext_vector_type(2)));

__device__ __forceinline__ void decode4(unsigned int pk, float& e0, float& e1, float& e2, float& e3) {
    v2f lo = __builtin_amdgcn_cvt_pk_f32_fp8((int)pk, false);
    v2f hi = __builtin_amdgcn_cvt_pk_f32_fp8((int)pk, true);
    e0 = lo.x; e1 = lo.y; e2 = hi.x; e3 = hi.y;
}

__device__ __forceinline__ int trans_idx(int w2w, int ic, int dist) {
    return (w2w == 1) ? 0 : (ic == 0 ? 1 : (dist == 0 ? 2 : 3));
}

// pack two floats into bf16 pair (RNE), x low half, y high half
__device__ __forceinline__ unsigned bf16pair(float x, float y) {
    unsigned ux = __float_as_uint(x);
    ux = (ux + 0x7fffu + ((ux >> 16) & 1u)) >> 16;
    unsigned uy = __float_as_uint(y);
    uy = (uy + 0x7fffu + ((uy >> 16) & 1u)) & 0xffff0000u;
    return ux | uy;
}

// fp8-e4m3 encode of exp(x) for x in ~[-0.6,0.6] (always positive normal)
__device__ __forceinline__ unsigned fp8exp(float x) {
    float ev = __expf(x);
    unsigned u = __float_as_uint(ev) - 0x3C000000u;          // rebias to e4m3 field at bit20
    return (u + 0x7FFFFu + ((u >> 20) & 1u)) >> 20;          // RNE
}

// ---- scan (fused: E self-staging + per-chunk gold + chunk scan) ----
// 512 threads = 4 pipes x 128 lanes sharing one fp8 LDS copy of all 4 E.
// E quad index Q = m*1024 + k4*128 + L; dword e of quad holds fp8x4 of
// exp(trans[m][32*(L>>5)+4*k4+e][4*(L&31)+j]), j=0..3.
// Pipe-lane tau: p=tau&31 (cols 4p..4p+3), h=tau>>5 (rows 32h..32h+31).
// v in LDS as bf16 pairs; renorm every 8 steps (bf16 has f32 exponent range).
__global__ void __launch_bounds__(512, 4) scan_kernel(
    const float* __restrict__ em, const float* __restrict__ trans,
    const float* __restrict__ start, const float* __restrict__ cw,
    const int* __restrict__ tags, const int* __restrict__ w2w,
    const int* __restrict__ ic, const int* __restrict__ dist,
    double* __restrict__ goldslots, double* __restrict__ logzslots)
{
    const int pipe = threadIdx.x >> 7;      // 0..3
    const int tau  = threadIdx.x & 127;     // pipe-local thread id
    const int c    = (blockIdx.x << 2) | pipe;
    const int p    = tau & 31;
    const int h    = tau >> 5;

    __shared__ uint4 EL[4096];                           // 64 KB: all 4 fp8 matrices
    __shared__ unsigned v16[4][64];                      // v as bf16 pairs, per pipe
    __shared__ __align__(16) float partial[4][4][KDIM];  // 8 KB
    __shared__ float wsum[4][2];
    __shared__ float gsum[4][2];

    // ---- stage E from trans (whole block; 8 quads/thread) ----
    #pragma unroll
    for (int w = 0; w < 8; ++w) {
        const int q  = (w << 9) + threadIdx.x;           // 0..4095
        const int m  = q >> 10, k4 = (q >> 7) & 7, L = q & 127;
        const int col = (L & 31) << 2;
        const int rbase = ((L >> 5) << 5) + (k4 << 2);
        const float* src = trans + ((size_t)m << 14) + (rbase << 7) + col;
        unsigned d[4];
        #pragma unroll
        for (int e = 0; e < 4; ++e) {
            unsigned out = 0;
            #pragma unroll
            for (int j = 0; j < 4; ++j)
                out |= (fp8exp(src[(e << 7) + j]) & 0xffu) << (8 * j);
            d[e] = out;
        }
        uint4 qq; qq.x = d[0]; qq.y = d[1]; qq.z = d[2]; qq.w = d[3];
        EL[q] = qq;
    }

    const int t_own = 1 + c * CHUNK;
    const int t_end = min(t_own + CHUNK, T_LEN);
    const int t0    = (c == 0) ? 1 : (t_own - WARM);

    // ---- gold slice for this chunk (idle-lane work) ----
    float gpart = 0.f;
    if (tau < CHUNK) {
        const int t = t_own + tau;
        if (t < t_end) {
            const int tg  = tags[t];
            const int tgp = tags[t - 1];
            const int m   = trans_idx(w2w[t - 1], ic[t - 1], dist[t - 1]);
            gpart = cw[tg] * (trans[((size_t)m * KDIM + tgp) * KDIM + tg] +
                              em[(size_t)t * KDIM + tg]);
        }
    } else if (c == 0 && tau == 64) {
        const int tg = tags[0];
        gpart = cw[tg] * (start[tg] + em[tg]);
    }
    {
        float r = gpart;
        #pragma unroll
        for (int off = 32; off; off >>= 1) r += __shfl_down(r, off, 64);
        if ((tau & 63) == 0) gsum[pipe][tau >> 6] = r;
    }

    // ---- init v ----
    float myv = (c == 0) ? __expf(start[tau] + em[tau]) : 1.0f;
    {
        const float other = __shfl_xor(myv, 1, 64);
        if (!(tau & 1)) v16[pipe][tau >> 1] = bf16pair(myv, other);
    }
    float r0 = myv;
    #pragma unroll
    for (int off = 32; off; off >>= 1) r0 += __shfl_down(r0, off, 64);
    if ((tau & 63) == 0) wsum[pipe][tau >> 6] = r0;
    __syncthreads();   // covers EL staging + gsum + v16 + wsum

    if (tau == 0) goldslots[c] = (double)(gsum[pipe][0] + gsum[pipe][1]);

    const float s0 = wsum[pipe][0] + wsum[pipe][1];
    float scale = 1.0f / s0;
    float g = (c == 0) ? __logf(s0) : 0.f;

    // ---- prefetch step t0 (m from 3 uniform loads; no idxArr) ----
    int pw = w2w[t0 - 1], pi = ic[t0 - 1], pd = dist[t0 - 1];
    float em_pref = em[(size_t)t0 * KDIM + tau];

    for (int it = 0; it < NSTEP; ++it) {
        const int t = t0 + it;
        const bool live = (t < t_end);
        const int m = trans_idx(pw, pi, pd);
        const float d = __expf(em_pref);

        // prefetch next step (clamped in-bounds)
        const int tn = min(t + 1, T_LEN - 1);
        pw = w2w[tn - 1]; pi = ic[tn - 1]; pd = dist[tn - 1];
        em_pref = em[(size_t)tn * KDIM + tau];

        // phase 1: 128 MACs: rows 32h..32h+31, cols 4p..4p+3
        const uint4* Eq = EL + (m << 10) + tau;
        const uint4* vq = reinterpret_cast<const uint4*>(&v16[pipe][h << 4]);
        float a0 = 0.f, a1 = 0.f, a2 = 0.f, a3 = 0.f;
        #pragma unroll
        for (int j2 = 0; j2 < 4; ++j2) {
            const uint4 vv = vq[j2];
            const uint4 qa = Eq[(j2 << 1) << 7];
            const uint4 qb = Eq[((j2 << 1) + 1) << 7];
            float e0, e1, e2, e3, w0, w1;
            w0 = __uint_as_float(vv.x << 16);  w1 = __uint_as_float(vv.x & 0xffff0000u);
            decode4(qa.x, e0, e1, e2, e3);
            a0 = fmaf(w0, e0, a0); a1 = fmaf(w0, e1, a1); a2 = fmaf(w0, e2, a2); a3 = fmaf(w0, e3, a3);
            decode4(qa.y, e0, e1, e2, e3);
            a0 = fmaf(w1, e0, a0); a1 = fmaf(w1, e1, a1); a2 = fmaf(w1, e2, a2); a3 = fmaf(w1, e3, a3);
            w0 = __uint_as_float(vv.y << 16);  w1 = __uint_as_float(vv.y & 0xffff0000u);
            decode4(qa.z, e0, e1, e2, e3);
            a0 = fmaf(w0, e0, a0); a1 = fmaf(w0, e1, a1); a2 = fmaf(w0, e2, a2); a3 = fmaf(w0, e3, a3);
            decode4(qa.w, e0, e1, e2, e3);
            a0 = fmaf(w1, e0, a0); a1 = fmaf(w1, e1, a1); a2 = fmaf(w1, e2, a2); a3 = fmaf(w1, e3, a3);
            w0 = __uint_as_float(vv.z << 16);  w1 = __uint_as_float(vv.z & 0xffff0000u);
            decode4(qb.x, e0, e1, e2, e3);
            a0 = fmaf(w0, e0, a0); a1 = fmaf(w0, e1, a1); a2 = fmaf(w0, e2, a2); a3 = fmaf(w0, e3, a3);
            decode4(qb.y, e0, e1, e2, e3);
            a0 = fmaf(w1, e0, a0); a1 = fmaf(w1, e1, a1); a2 = fmaf(w1, e2, a2); a3 = fmaf(w1, e3, a3);
            w0 = __uint_as_float(vv.w << 16);  w1 = __uint_as_float(vv.w & 0xffff0000u);
            decode4(qb.z, e0, e1, e2, e3);
            a0 = fmaf(w0, e0, a0); a1 = fmaf(w0, e1, a1); a2 = fmaf(w0, e2, a2); a3 = fmaf(w0, e3, a3);
            decode4(qb.w, e0, e1, e2, e3);
            a0 = fmaf(w1, e0, a0); a1 = fmaf(w1, e1, a1); a2 = fmaf(w1, e2, a2); a3 = fmaf(w1, e3, a3);
        }
        *reinterpret_cast<float4*>(&partial[pipe][h][p << 2]) = make_float4(a0, a1, a2, a3);
        __syncthreads();

        // phase 2: combine 4 partials, emission + pending scale, repack v
        const bool donorm = ((t & 7) == 0) || (t == T_LEN - 1);
        const float tot = (partial[pipe][0][tau] + partial[pipe][1][tau] +
                           partial[pipe][2][tau] + partial[pipe][3][tau]) * (d * scale);
        {
            const float other = __shfl_xor(tot, 1, 64);
            if (live && !(tau & 1)) v16[pipe][tau >> 1] = bf16pair(tot, other);
        }
        if (donorm) {
            float r = tot;
            #pragma unroll
            for (int off = 32; off; off >>= 1) r += __shfl_down(r, off, 64);
            if ((tau & 63) == 0) wsum[pipe][tau >> 6] = r;
        }
        __syncthreads();
        if (donorm) {
            const float s = wsum[pipe][0] + wsum[pipe][1];
            scale = 1.0f / s;
            if (tau == 0 && t >= t_own && t < t_end) g += __logf(s);
        } else {
            scale = 1.0f;
        }
    }

    if (tau == 0) logzslots[c] = (double)g;
}

__global__ void finalize_kernel(const double* __restrict__ goldslots,
                                const double* __restrict__ logzslots,
                                float* __restrict__ out) {
    __shared__ double red[256];
    const int i = threadIdx.x;
    double a = 0.0;
    #pragma unroll
    for (int k = 0; k < 8; ++k) a += goldslots[i + (k << 8)];
    red[i] = a;
    __syncthreads();
    for (int s = 128; s > 0; s >>= 1) {
        if (i < s) red[i] += red[i + s];
        __syncthreads();
    }
    if (i == 0) out[0] = (float)red[0];
    __syncthreads();
    double b = 0.0;
    #pragma unroll
    for (int k = 0; k < 8; ++k) b += logzslots[i + (k << 8)];
    red[i] = b;
    __syncthreads();
    for (int s = 128; s > 0; s >>= 1) {
        if (i < s) red[i] += red[i + s];
        __syncthreads();
    }
    if (i == 0) out[1] = (float)red[0];
}

extern "C" void kernel_launch(void* const* d_in, const int* in_sizes, int n_in,
                              void* d_out, int out_size, void* d_ws, size_t ws_size,
                              hipStream_t stream) {
    const float* emissions = (const float*)d_in[0];
    const float* trans     = (const float*)d_in[1];
    const float* start     = (const float*)d_in[2];
    const float* cw        = (const float*)d_in[3];
    const int*   tags      = (const int*)d_in[4];
    const int*   w2w       = (const int*)d_in[5];
    const int*   icnt      = (const int*)d_in[6];
    const int*   dist      = (const int*)d_in[7];

    double* goldslots = (double*)d_ws;            // 2048 doubles
    double* logzslots = (double*)d_ws + 2048;     // 2048 doubles

    scan_kernel<<<NCHUNK / 4, 512, 0, stream>>>(emissions, trans, start, cw, tags,
                                                w2w, icnt, dist, goldslots, logzslots);
    finalize_kernel<<<1, 256, 0, stream>>>(goldslots, logzslots, (float*)d_out);
}